// Round 1
// 103.594 us; speedup vs baseline: 1.0126x; 1.0126x over previous
//
#include <hip/hip_runtime.h>
#include <stdint.h>

// Problem constants (B,C,H,W)=(8,64,128,128), OC=64, K=3, stride=1, pad=1, fill=-1.
#define HW   128
#define CIN  64
#define OCN  64
#define NB   8

typedef __attribute__((ext_vector_type(8)))  short short8;
typedef __attribute__((ext_vector_type(16))) float floatx16;
typedef unsigned long long u64;

union F8 { short8 s; u64 u[2]; uint32_t d[4]; uint4 q; };

// round-to-nearest-even f32 -> bf16 (inputs are finite; no NaN path needed)
static __device__ __forceinline__ ushort f2bf(float f) {
    uint32_t u = __float_as_uint(f);
    uint32_t r = (u + 0x7FFFu + ((u >> 16) & 1u)) >> 16;
    return (ushort)r;
}

// ---------- prepass: conv[oc][c][kh][kw] fp32 -> A-fragment-ordered bf16 ----------
// wb[((t*4+ks)*2+m)*512 + lane*8 + j] = bf16(W[m*32+(lane&31)][ks*16+(lane>>5)*8+j], tap t)
// so the main kernel's per-lane A fragment is ONE coalesced 16B global load,
// identical across waves/blocks (L1/L2 broadcast). No LDS A tile, no in-loop barriers.
__global__ void wprep_kernel(const float* __restrict__ conv, ushort* __restrict__ wb) {
    int idx  = blockIdx.x * 256 + threadIdx.x;   // 0..36863 (= 9*8*512), grid sized exactly
    int j    = idx & 7;
    int lane = (idx >> 3) & 63;
    int m    = (idx >> 9) & 1;
    int ks   = (idx >> 10) & 3;
    int t    = idx >> 12;
    int oc   = m * 32 + (lane & 31);
    int c    = ks * 16 + (lane >> 5) * 8 + j;
    wb[idx] = f2bf(conv[(oc * 64 + c) * 9 + t]);
}

// ---------- main fused kernel ----------
// block = (batch b, row-pair y0,y0+1). 256 threads = 4 waves.
// wave w: yloc=w>>1 (row), xw=(w&1)*64 ; wave tile = 64 oc x 64 px.
#define XS_CSTR 68                 // shorts per pixel (64 + pad4) -> 136B stride (2-way-free banks)
#define XS_ROW  (HW * XS_CSTR)     // 8704 shorts per staged row
#define LDS_BYTES 71936            // Xs 69632 + Ms 2048 + Bb 256

__global__ __launch_bounds__(256, 2)
void iconv_main(const float* __restrict__ inp, const float* __restrict__ mask,
                const ushort* __restrict__ wb, const float* __restrict__ bias,
                float* __restrict__ out)
{
    extern __shared__ char smem[];
    ushort* Xs = (ushort*)smem;                       // 4 rows * 8704 shorts = 69632 B
    float*  Ms = (float*)(smem + 69632);              // 4*128 floats = 2048 B
    float*  Bb = (float*)(smem + 71680);              // 64 floats

    const int tid  = threadIdx.x;
    const int bb   = blockIdx.x >> 6;
    const int y0   = (blockIdx.x & 63) << 1;
    const int lane = tid & 63;
    const int l31  = lane & 31;
    const int lh   = lane >> 5;
    const int w    = tid >> 6;
    const int yloc = w >> 1;
    const int xw   = (w & 1) * 64;
    const int y    = y0 + yloc;

    // A fragments for tap 0: issue early, they resolve while X stages.
    const ushort* aBase = wb + lane * 8;
    uint4 a_cur[8];
    #pragma unroll
    for (int f = 0; f < 8; ++f)
        a_cur[f] = *(const uint4*)(aBase + f * 512);

    // ---- stage X: rows y0-1 .. y0+2, NCHW fp32 -> LDS [row][x][c] bf16 ----
    {
        const int cp = tid & 31;            // c pair: c = 2cp, 2cp+1
        const int xq = (tid >> 5) * 16;     // 16 x per thread
        const float* base0 = inp + ((size_t)(bb * CIN + 2 * cp) * HW) * HW;
        #pragma unroll
        for (int rr = 0; rr < 4; ++rr) {
            int gy = y0 - 1 + rr;
            if (gy >= 0 && gy < HW) {
                const float4* q0 = (const float4*)(base0 + (size_t)gy * HW + xq);
                const float4* q1 = (const float4*)(base0 + (size_t)HW * HW + (size_t)gy * HW + xq);
                float4 v0[4], v1[4];
                #pragma unroll
                for (int i = 0; i < 4; ++i) { v0[i] = q0[i]; v1[i] = q1[i]; }
                ushort* xrow = Xs + rr * XS_ROW + xq * XS_CSTR + 2 * cp;
                const float* f0 = (const float*)v0;
                const float* f1 = (const float*)v1;
                #pragma unroll
                for (int i = 0; i < 16; ++i) {
                    uint32_t p = (uint32_t)f2bf(f0[i]) | ((uint32_t)f2bf(f1[i]) << 16);
                    *(uint32_t*)(xrow + i * XS_CSTR) = p;
                }
            }
        }
    }
    // ---- stage mask rows ----
    {
        int rr = tid >> 6, x0 = (tid & 63) * 2;
        int gy = y0 - 1 + rr;
        if (gy >= 0 && gy < HW) {
            float2 v = *(const float2*)(mask + ((size_t)bb * HW + gy) * HW + x0);
            Ms[rr * HW + x0]     = v.x;
            Ms[rr * HW + x0 + 1] = v.y;
        }
    }
    if (tid < OCN) Bb[tid] = bias[tid];

    __syncthreads();                       // the ONLY barrier

    // ---- mask_out (second output slot): rows y0, y0+1 straight from Ms ----
    {
        int yy = tid >> 7, x = tid & 127;
        float mv = Ms[(1 + yy) * HW + x];
        __builtin_nontemporal_store(
            mv, out + (size_t)NB * OCN * HW * HW + ((size_t)bb * HW + y0 + yy) * HW + x);
    }

    // ---- per-lane eq masks and norms (2 pixels per lane) ----
    uint32_t sel[9][2];
    float norm0, norm1;
    {
        int cnt0 = 0, cnt1 = 0;
        int xq0 = xw + l31, xq1 = xw + 32 + l31;
        float m00 = Ms[(1 + yloc) * HW + xq0];
        float m01 = Ms[(1 + yloc) * HW + xq1];
        #pragma unroll
        for (int t = 0; t < 9; ++t) {
            int dy = t / 3 - 1, dx = t % 3 - 1;
            int ny = y + dy;
            bool vy = (ny >= 0) && (ny < HW);
            int rbase = (1 + yloc + dy) * HW;
            {
                int nx = xq0 + dx;
                bool ok = vy && (nx >= 0) && (nx < HW);
                int nxc = nx < 0 ? 0 : (nx > HW - 1 ? HW - 1 : nx);
                bool eq = ok && (Ms[rbase + nxc] == m00);
                sel[t][0] = eq ? 0xFFFFFFFFu : 0u;
                cnt0 += eq ? 1 : 0;
            }
            {
                int nx = xq1 + dx;
                bool ok = vy && (nx >= 0) && (nx < HW);
                int nxc = nx < 0 ? 0 : (nx > HW - 1 ? HW - 1 : nx);
                bool eq = ok && (Ms[rbase + nxc] == m01);
                sel[t][1] = eq ? 0xFFFFFFFFu : 0u;
                cnt1 += eq ? 1 : 0;
            }
        }
        norm0 = 9.0f / (float)cnt0;
        norm1 = 9.0f / (float)cnt1;
    }

    floatx16 acc00 = {0,0,0,0,0,0,0,0,0,0,0,0,0,0,0,0};
    floatx16 acc01 = {0,0,0,0,0,0,0,0,0,0,0,0,0,0,0,0};
    floatx16 acc10 = {0,0,0,0,0,0,0,0,0,0,0,0,0,0,0,0};
    floatx16 acc11 = {0,0,0,0,0,0,0,0,0,0,0,0,0,0,0,0};

    // ---- barrier-free tap loop: A from global (L1/L2 broadcast), B from LDS ----
    #pragma unroll
    for (int t = 0; t < 9; ++t) {
        uint4 a_nxt[8];
        if (t < 8) {                         // prefetch next tap under this tap's MFMAs
            #pragma unroll
            for (int f = 0; f < 8; ++f)
                a_nxt[f] = *(const uint4*)(aBase + ((t + 1) * 8 + f) * 512);
        }

        const int dy = t / 3 - 1, dx = t % 3 - 1;
        const int rrB = 1 + yloc + dy;        // 0..3
        int xa = xw + l31 + dx;
        int xb0c = xa < 0 ? 0 : (xa > HW - 1 ? HW - 1 : xa);
        int xa1 = xa + 32;
        int xb1c = xa1 < 0 ? 0 : (xa1 > HW - 1 ? HW - 1 : xa1);
        const ushort* B0p = Xs + rrB * XS_ROW + xb0c * XS_CSTR + lh * 8;
        const ushort* B1p = Xs + rrB * XS_ROW + xb1c * XS_CSTR + lh * 8;
        const uint32_t s0 = sel[t][0], s1 = sel[t][1];

        #pragma unroll
        for (int ks = 0; ks < 4; ++ks) {      // 4 K-steps of 16 channels
            F8 a0, a1, b0, b1;
            a0.q = a_cur[ks * 2 + 0];
            a1.q = a_cur[ks * 2 + 1];
            b0.u[0] = *(const u64*)(B0p + ks * 16);
            b0.u[1] = *(const u64*)(B0p + ks * 16 + 4);
            b1.u[0] = *(const u64*)(B1p + ks * 16);
            b1.u[1] = *(const u64*)(B1p + ks * 16 + 4);
            b0.d[0] &= s0; b0.d[1] &= s0; b0.d[2] &= s0; b0.d[3] &= s0;
            b1.d[0] &= s1; b1.d[1] &= s1; b1.d[2] &= s1; b1.d[3] &= s1;
            acc00 = __builtin_amdgcn_mfma_f32_32x32x16_bf16(a0.s, b0.s, acc00, 0, 0, 0);
            acc01 = __builtin_amdgcn_mfma_f32_32x32x16_bf16(a0.s, b1.s, acc01, 0, 0, 0);
            acc10 = __builtin_amdgcn_mfma_f32_32x32x16_bf16(a1.s, b0.s, acc10, 0, 0, 0);
            acc11 = __builtin_amdgcn_mfma_f32_32x32x16_bf16(a1.s, b1.s, acc11, 0, 0, 0);
        }

        #pragma unroll
        for (int f = 0; f < 8; ++f)
            if (t < 8) a_cur[f] = a_nxt[f];   // SSA-renamed away by the full unroll
    }

    // ---- epilogue: norm, bias, store (C/D: col=lane&31, row=(r&3)+8*(r>>2)+4*lh) ----
    // nontemporal: streamed output, keep L2 for neighbor-block input-row reuse
    float* outp = out + (size_t)bb * OCN * HW * HW + (size_t)y * HW;
    #pragma unroll
    for (int mt = 0; mt < 2; ++mt) {
        #pragma unroll
        for (int nt = 0; nt < 2; ++nt) {
            floatx16 a = (mt == 0) ? (nt == 0 ? acc00 : acc01)
                                   : (nt == 0 ? acc10 : acc11);
            float nm = (nt == 0) ? norm0 : norm1;
            int x = xw + nt * 32 + l31;
            #pragma unroll
            for (int r = 0; r < 16; ++r) {
                int oc = mt * 32 + (r & 3) + 8 * (r >> 2) + 4 * lh;
                __builtin_nontemporal_store(a[r] * nm + Bb[oc],
                                            outp + (size_t)oc * (HW * HW) + x);
            }
        }
    }
}

extern "C" void kernel_launch(void* const* d_in, const int* in_sizes, int n_in,
                              void* d_out, int out_size, void* d_ws, size_t ws_size,
                              hipStream_t stream) {
    (void)in_sizes; (void)n_in; (void)out_size; (void)ws_size;
    const float* inp  = (const float*)d_in[0];
    const float* mask = (const float*)d_in[1];
    const float* conv = (const float*)d_in[2];
    const float* bias = (const float*)d_in[3];
    float* out = (float*)d_out;
    ushort* wb = (ushort*)d_ws;               // 9*8*512 bf16 = 73,728 B

    // dynamic-LDS cap (>64KB). Function-attribute API, not a stream op: capture-safe.
    hipFuncSetAttribute((const void*)iconv_main,
                        hipFuncAttributeMaxDynamicSharedMemorySize, LDS_BYTES);

    wprep_kernel<<<144, 256, 0, stream>>>(conv, wb);
    iconv_main<<<NB * (HW / 2), 256, LDS_BYTES, stream>>>(inp, mask, wb, bias, out);
    // mask_out is written inside iconv_main (d2d memcpy dispatch removed)
}